// Round 4
// baseline (1006.418 us; speedup 1.0000x reference)
//
#include <hip/hip_runtime.h>
#include <hip/hip_bf16.h>

#define N_NODES 50000
#define N_EDGES 800000
#define HIDDEN  256
#define N_GRAPHS 128

typedef short bf16x8 __attribute__((ext_vector_type(8)));
typedef float f32x4 __attribute__((ext_vector_type(4)));

// ---- bf16 split helpers (RNE) ----
__device__ __forceinline__ void bf_split(float x, unsigned short& hi, unsigned short& lo) {
    union { float f; unsigned u; } a; a.f = x;
    unsigned short h16 = (unsigned short)((a.u + 0x7FFFu + ((a.u >> 16) & 1u)) >> 16);
    union { float f; unsigned u; } hf; hf.u = ((unsigned)h16) << 16;
    float res = x - hf.f;
    union { float f; unsigned u; } b; b.f = res;
    unsigned short l16 = (unsigned short)((b.u + 0x7FFFu + ((b.u >> 16) & 1u)) >> 16);
    hi = h16; lo = l16;
}

// ---------------- degree / norm ----------------
__global__ void deg_count_kernel(const int* __restrict__ ei, int* __restrict__ deg) {
    int e = blockIdx.x * blockDim.x + threadIdx.x;
    if (e < N_EDGES) atomicAdd(&deg[ei[N_EDGES + e]], 1);
}

__global__ void dinv_kernel(const int* __restrict__ deg, float* __restrict__ dinv) {
    int i = blockIdx.x * blockDim.x + threadIdx.x;
    if (i < N_NODES) dinv[i] = rsqrtf((float)(deg[i] + 1)); // +1 = self loop
}

// ---------------- hierarchical scan ----------------
__global__ __launch_bounds__(256) void block_scan_kernel(const int* __restrict__ deg,
                                                         int* __restrict__ rowptr,
                                                         int* __restrict__ bsums) {
    __shared__ int s[256];
    int tid = threadIdx.x;
    int i = blockIdx.x * 256 + tid;
    int v = (i < N_NODES) ? deg[i] : 0;
    s[tid] = v;
    __syncthreads();
#pragma unroll
    for (int ofs = 1; ofs < 256; ofs <<= 1) {
        int t = (tid >= ofs) ? s[tid - ofs] : 0;
        __syncthreads();
        s[tid] += t;
        __syncthreads();
    }
    if (i < N_NODES) rowptr[i + 1] = s[tid];
    if (tid == 255) bsums[blockIdx.x] = s[255];
}

__global__ __launch_bounds__(256) void scan_bsums_kernel(int* __restrict__ bsums, int nb) {
    __shared__ int s[256];
    int tid = threadIdx.x;
    int v = (tid < nb) ? bsums[tid] : 0;
    s[tid] = v;
    __syncthreads();
#pragma unroll
    for (int ofs = 1; ofs < 256; ofs <<= 1) {
        int t = (tid >= ofs) ? s[tid - ofs] : 0;
        __syncthreads();
        s[tid] += t;
        __syncthreads();
    }
    if (tid < nb) bsums[tid] = (tid == 0) ? 0 : s[tid - 1];
}

__global__ __launch_bounds__(256) void add_offsets_kernel(int* __restrict__ rowptr,
                                                          const int* __restrict__ bsums) {
    int i = blockIdx.x * 256 + threadIdx.x;
    if (i == 0) rowptr[0] = 0;
    if (i < N_NODES) rowptr[i + 1] += bsums[blockIdx.x];
}

__global__ void fill_csr_kernel(const int* __restrict__ ei, const int* __restrict__ rowptr,
                                int* __restrict__ cursor, const float* __restrict__ dinv,
                                int* __restrict__ csr_src, float* __restrict__ csr_norm) {
    int e = blockIdx.x * blockDim.x + threadIdx.x;
    if (e < N_EDGES) {
        int s = ei[e];
        int d = ei[N_EDGES + e];
        int p = rowptr[d] + atomicAdd(&cursor[d], 1);
        csr_src[p] = s;
        csr_norm[p] = dinv[s] * dinv[d];
    }
}

// ---------------- conv1: aggregate 2-ch x, then expand to split-bf16 ----------------
__global__ void aggx_kernel(const float* __restrict__ x, const int* __restrict__ rowptr,
                            const int* __restrict__ csr_src, const float* __restrict__ csr_norm,
                            const float* __restrict__ dinv, float* __restrict__ ax) {
    int i = blockIdx.x * blockDim.x + threadIdx.x;
    if (i >= N_NODES) return;
    float di = dinv[i];
    float w0 = di * di;
    float a0 = x[2 * i] * w0, a1 = x[2 * i + 1] * w0;
    int e0 = rowptr[i], e1 = rowptr[i + 1];
    for (int p = e0; p < e1; ++p) {
        int s = csr_src[p];
        float w = csr_norm[p];
        a0 += x[2 * s] * w;
        a1 += x[2 * s + 1] * w;
    }
    ax[2 * i] = a0;
    ax[2 * i + 1] = a1;
}

__global__ void expand1_split_kernel(const float* __restrict__ ax, const float* __restrict__ W1,
                                     const float* __restrict__ b1,
                                     unsigned short* __restrict__ rhi,
                                     unsigned short* __restrict__ rlo) {
    int idx = blockIdx.x * blockDim.x + threadIdx.x;
    if (idx >= N_NODES * HIDDEN) return;
    int i = idx >> 8, c = idx & 255;
    float h = ax[2 * i] * W1[c] + ax[2 * i + 1] * W1[HIDDEN + c] + b1[c];
    float r = fmaxf(h, 0.f);
    unsigned short hh, ll;
    bf_split(r, hh, ll);
    rhi[idx] = hh;
    rlo[idx] = ll;
}

// ---------------- W split+transpose (once per call): WT[n][k] bf16 hi/lo ----------------
__global__ void wsplit_kernel(const float* __restrict__ W2, const float* __restrict__ W3,
                              const float* __restrict__ W4,
                              unsigned short* __restrict__ whiT,
                              unsigned short* __restrict__ wloT) {
    int which = blockIdx.y;
    const float* W = (which == 0) ? W2 : ((which == 1) ? W3 : W4);
    unsigned short* hT = whiT + which * 65536;
    unsigned short* lT = wloT + which * 65536;
    int n = blockIdx.x, k = threadIdx.x;
    float v = W[k * 256 + n];
    unsigned short hh, ll;
    bf_split(v, hh, ll);
    hT[n * 256 + k] = hh;
    lT[n * 256 + k] = ll;
}

// ---------------- MFMA GEMM: t = r @ W via 3 split products ----------------
// t = rhi*Whi + rhi*Wlo + rlo*Whi. 128x128 tile, 4 waves, 64x64/wave, K-chunk 64.
__global__ __launch_bounds__(256) void mfma_gemm_kernel(const unsigned short* __restrict__ rhi,
                                                        const unsigned short* __restrict__ rlo,
                                                        const unsigned short* __restrict__ whiT,
                                                        const unsigned short* __restrict__ wloT,
                                                        float* __restrict__ t) {
    __shared__ short As[128][72]; // padded row: 72*2B=144B -> banks shift 4/row (2-way max reads)
    __shared__ short Bs[128][72];
    int tid = threadIdx.x;
    int row0 = blockIdx.x * 128;
    int col0 = blockIdx.y * 128;
    int lane = tid & 63;
    int wave = tid >> 6;
    int wm = wave >> 1, wn = wave & 1;
    int wq = lane >> 4, lm = lane & 15;

    const unsigned short* Aseg[3] = {rhi, rhi, rlo};
    const unsigned short* Bseg[3] = {whiT, wloT, whiT};

    // staging: thread covers row tid>>1, k-half (tid&1)*32, 4 x float4
    int r = tid >> 1;
    int hh = tid & 1;
    int grow = row0 + r; if (grow >= N_NODES) grow = N_NODES - 1;
    int ncol = col0 + r;
    size_t aoff = (size_t)grow * 256 + hh * 32;
    size_t boff = (size_t)ncol * 256 + hh * 32;

    f32x4 acc[4][4];
#pragma unroll
    for (int mi = 0; mi < 4; ++mi)
#pragma unroll
        for (int ni = 0; ni < 4; ++ni) acc[mi][ni] = (f32x4)0.f;

    float4 pa[4], pb[4];
#pragma unroll
    for (int j = 0; j < 4; ++j) {
        pa[j] = *(const float4*)(rhi + aoff + j * 8);
        pb[j] = *(const float4*)(whiT + boff + j * 8);
    }

    for (int cc = 0; cc < 12; ++cc) {
        __syncthreads();
#pragma unroll
        for (int j = 0; j < 4; ++j) {
            *(float4*)&As[r][hh * 32 + j * 8] = pa[j];
            *(float4*)&Bs[r][hh * 32 + j * 8] = pb[j];
        }
        __syncthreads();
        if (cc + 1 < 12) {
            int nc = cc + 1;
            int sg = nc >> 2;
            int kk = (nc & 3) * 64;
            const unsigned short* Ab = Aseg[sg];
            const unsigned short* Bb = Bseg[sg];
#pragma unroll
            for (int j = 0; j < 4; ++j) {
                pa[j] = *(const float4*)(Ab + aoff + kk + j * 8);
                pb[j] = *(const float4*)(Bb + boff + kk + j * 8);
            }
        }
#pragma unroll
        for (int s = 0; s < 2; ++s) {
            bf16x8 af[4], bf[4];
#pragma unroll
            for (int mi = 0; mi < 4; ++mi)
                af[mi] = *(const bf16x8*)&As[wm * 64 + mi * 16 + lm][s * 32 + wq * 8];
#pragma unroll
            for (int ni = 0; ni < 4; ++ni)
                bf[ni] = *(const bf16x8*)&Bs[wn * 64 + ni * 16 + lm][s * 32 + wq * 8];
#pragma unroll
            for (int mi = 0; mi < 4; ++mi)
#pragma unroll
                for (int ni = 0; ni < 4; ++ni)
                    acc[mi][ni] = __builtin_amdgcn_mfma_f32_16x16x32_bf16(af[mi], bf[ni],
                                                                          acc[mi][ni], 0, 0, 0);
        }
    }

#pragma unroll
    for (int mi = 0; mi < 4; ++mi) {
        int r0 = row0 + wm * 64 + mi * 16 + wq * 4;
#pragma unroll
        for (int ni = 0; ni < 4; ++ni) {
            int col = col0 + wn * 64 + ni * 16 + lm;
#pragma unroll
            for (int rr = 0; rr < 4; ++rr) {
                int gr = r0 + rr;
                if (gr < N_NODES) t[(size_t)gr * 256 + col] = acc[mi][ni][rr];
            }
        }
    }
}

// ---------------- full-row aggregation, wave per node ----------------
// out[i,:] = sum_e t[src,:]*w + t[i,:]*dinv^2 + b; epilogue: split-relu-bf16 or fp32 (LAST)
template <int LAST>
__global__ __launch_bounds__(256) void agg_full_kernel(const float* __restrict__ t,
                                                       const int* __restrict__ rowptr,
                                                       const int* __restrict__ csr_src,
                                                       const float* __restrict__ csr_norm,
                                                       const float* __restrict__ dinv,
                                                       const float* __restrict__ bias,
                                                       float* __restrict__ hout,
                                                       unsigned short* __restrict__ rhi,
                                                       unsigned short* __restrict__ rlo) {
    int node = blockIdx.x * 4 + (threadIdx.x >> 6);
    if (node >= N_NODES) return;
    int lane = threadIdx.x & 63;
    int c = lane * 4;
    float di = dinv[node];
    float w0 = di * di;
    float4 v = *(const float4*)&t[(size_t)node * HIDDEN + c];
    float4 acc = make_float4(v.x * w0, v.y * w0, v.z * w0, v.w * w0);
    int e0 = rowptr[node], e1 = rowptr[node + 1];
    int p = e0;
    for (; p + 4 <= e1; p += 4) {
        int s0 = csr_src[p + 0], s1 = csr_src[p + 1];
        int s2 = csr_src[p + 2], s3 = csr_src[p + 3];
        float n0 = csr_norm[p + 0], n1 = csr_norm[p + 1];
        float n2 = csr_norm[p + 2], n3 = csr_norm[p + 3];
        float4 u0 = *(const float4*)&t[(size_t)s0 * HIDDEN + c];
        float4 u1 = *(const float4*)&t[(size_t)s1 * HIDDEN + c];
        float4 u2 = *(const float4*)&t[(size_t)s2 * HIDDEN + c];
        float4 u3 = *(const float4*)&t[(size_t)s3 * HIDDEN + c];
        acc.x += u0.x * n0; acc.y += u0.y * n0; acc.z += u0.z * n0; acc.w += u0.w * n0;
        acc.x += u1.x * n1; acc.y += u1.y * n1; acc.z += u1.z * n1; acc.w += u1.w * n1;
        acc.x += u2.x * n2; acc.y += u2.y * n2; acc.z += u2.z * n2; acc.w += u2.w * n2;
        acc.x += u3.x * n3; acc.y += u3.y * n3; acc.z += u3.z * n3; acc.w += u3.w * n3;
    }
    for (; p < e1; ++p) {
        int s = csr_src[p];
        float w = csr_norm[p];
        float4 u = *(const float4*)&t[(size_t)s * HIDDEN + c];
        acc.x += u.x * w; acc.y += u.y * w; acc.z += u.z * w; acc.w += u.w * w;
    }
    float4 b4 = *(const float4*)&bias[c];
    acc.x += b4.x; acc.y += b4.y; acc.z += b4.z; acc.w += b4.w;

    if (LAST) {
        *(float4*)&hout[(size_t)node * HIDDEN + c] = acc;
    } else {
        float r0 = fmaxf(acc.x, 0.f), r1 = fmaxf(acc.y, 0.f);
        float r2 = fmaxf(acc.z, 0.f), r3 = fmaxf(acc.w, 0.f);
        ushort4 h4, l4;
        bf_split(r0, h4.x, l4.x);
        bf_split(r1, h4.y, l4.y);
        bf_split(r2, h4.z, l4.z);
        bf_split(r3, h4.w, l4.w);
        *(ushort4*)&rhi[(size_t)node * HIDDEN + c] = h4;
        *(ushort4*)&rlo[(size_t)node * HIDDEN + c] = l4;
    }
}

// ---------------- pooling ----------------
__global__ void bounds_kernel(const int* __restrict__ batch, int* __restrict__ gbounds) {
    int i = blockIdx.x * blockDim.x + threadIdx.x;
    if (i >= N_NODES) return;
    int bi = batch[i];
    int bprev = (i == 0) ? -1 : batch[i - 1];
    for (int g = bprev + 1; g <= bi; ++g) gbounds[g] = i;
    if (i == N_NODES - 1) {
        for (int g = bi + 1; g <= N_GRAPHS; ++g) gbounds[g] = N_NODES;
    }
}

__global__ __launch_bounds__(256) void pool_kernel(const float* __restrict__ h,
                                                   const int* __restrict__ gbounds,
                                                   float* __restrict__ gsum) {
    int g = blockIdx.x;
    int c = threadIdx.x;
    int s = gbounds[g], e = gbounds[g + 1];
    float acc = 0.f;
    int i = s;
    for (; i + 4 <= e; i += 4) {
        float v0 = h[(size_t)(i + 0) * HIDDEN + c];
        float v1 = h[(size_t)(i + 1) * HIDDEN + c];
        float v2 = h[(size_t)(i + 2) * HIDDEN + c];
        float v3 = h[(size_t)(i + 3) * HIDDEN + c];
        acc += v0 + v1 + v2 + v3;
    }
    for (; i < e; ++i) acc += h[(size_t)i * HIDDEN + c];
    float cnt = (float)(e - s);
    gsum[g * HIDDEN + c] = acc / fmaxf(cnt, 1.f);
}

// ---------------- MLP head ----------------
__global__ __launch_bounds__(128) void mlp_kernel(const float* __restrict__ gsum,
                                                  const float* __restrict__ lin1_w,
                                                  const float* __restrict__ lin1_b,
                                                  const float* __restrict__ lin2_w,
                                                  const float* __restrict__ lin2_b,
                                                  float* __restrict__ out) {
    __shared__ float grow[HIDDEN];
    __shared__ float red[2];
    int g = blockIdx.x, j = threadIdx.x;
    grow[j] = gsum[g * HIDDEN + j];
    grow[j + 128] = gsum[g * HIDDEN + j + 128];
    __syncthreads();
    float acc = lin1_b[j];
    for (int k = 0; k < HIDDEN; ++k) acc += grow[k] * lin1_w[k * 128 + j];
    acc = fmaxf(acc, 0.f);
    float v = acc * lin2_w[j];
#pragma unroll
    for (int ofs = 32; ofs > 0; ofs >>= 1) v += __shfl_down(v, ofs, 64);
    if ((j & 63) == 0) red[j >> 6] = v;
    __syncthreads();
    if (j == 0) out[g] = red[0] + red[1] + lin2_b[0];
}

// ---------------- launch ----------------
extern "C" void kernel_launch(void* const* d_in, const int* in_sizes, int n_in,
                              void* d_out, int out_size, void* d_ws, size_t ws_size,
                              hipStream_t stream) {
    const float* x      = (const float*)d_in[0];
    const int*   ei     = (const int*)d_in[1];
    const int*   batch  = (const int*)d_in[2];
    const float* W1     = (const float*)d_in[3];
    const float* b1     = (const float*)d_in[4];
    const float* W2     = (const float*)d_in[5];
    const float* b2     = (const float*)d_in[6];
    const float* W3     = (const float*)d_in[7];
    const float* b3     = (const float*)d_in[8];
    const float* W4     = (const float*)d_in[9];
    const float* b4     = (const float*)d_in[10];
    const float* lin1_w = (const float*)d_in[11];
    const float* lin1_b = (const float*)d_in[12];
    const float* lin2_w = (const float*)d_in[13];
    const float* lin2_b = (const float*)d_in[14];
    float* out = (float*)d_out;

    char* ws = (char*)d_ws;
    size_t off = 0;
    auto alloc = [&](size_t bytes) -> void* {
        void* p = ws + off;
        off += (bytes + 255) & ~(size_t)255;
        return p;
    };
    float*          tbuf   = (float*)alloc((size_t)N_NODES * HIDDEN * 4);   // 51.2 MB
    void*           rgn    = alloc((size_t)N_NODES * HIDDEN * 4);           // 51.2 MB (rhi+rlo | hfin)
    unsigned short* rhi    = (unsigned short*)rgn;
    unsigned short* rlo    = rhi + (size_t)N_NODES * HIDDEN;
    float*          hfin   = (float*)rgn;
    float* csr_norm = (float*)alloc((size_t)N_EDGES * 4);
    int*   csr_src  = (int*)alloc((size_t)N_EDGES * 4);
    int*   rowptr   = (int*)alloc((size_t)(N_NODES + 1) * 4);
    int*   deg      = (int*)alloc((size_t)N_NODES * 4);
    int*   cursor   = (int*)alloc((size_t)N_NODES * 4);
    float* dinv     = (float*)alloc((size_t)N_NODES * 4);
    float* ax       = (float*)alloc((size_t)N_NODES * 2 * 4);
    float* gsum     = (float*)alloc((size_t)N_GRAPHS * HIDDEN * 4);
    int*   gbounds  = (int*)alloc((size_t)(N_GRAPHS + 1) * 4);
    int*   bsums    = (int*)alloc((size_t)256 * 4);
    unsigned short* whiT = (unsigned short*)alloc((size_t)3 * 65536 * 2);
    unsigned short* wloT = (unsigned short*)alloc((size_t)3 * 65536 * 2);

    hipMemsetAsync(deg, 0, (size_t)N_NODES * 4, stream);
    hipMemsetAsync(cursor, 0, (size_t)N_NODES * 4, stream);

    const int TB = 256;
    const int NBLK = (N_NODES + 255) / 256;
    deg_count_kernel<<<(N_EDGES + TB - 1) / TB, TB, 0, stream>>>(ei, deg);
    dinv_kernel<<<(N_NODES + TB - 1) / TB, TB, 0, stream>>>(deg, dinv);
    block_scan_kernel<<<NBLK, 256, 0, stream>>>(deg, rowptr, bsums);
    scan_bsums_kernel<<<1, 256, 0, stream>>>(bsums, NBLK);
    add_offsets_kernel<<<NBLK, 256, 0, stream>>>(rowptr, bsums);
    fill_csr_kernel<<<(N_EDGES + TB - 1) / TB, TB, 0, stream>>>(ei, rowptr, cursor, dinv,
                                                                csr_src, csr_norm);
    wsplit_kernel<<<dim3(256, 3), 256, 0, stream>>>(W2, W3, W4, whiT, wloT);

    // conv1: (A x) W1 + b1 -> relu -> split bf16
    aggx_kernel<<<(N_NODES + TB - 1) / TB, TB, 0, stream>>>(x, rowptr, csr_src, csr_norm, dinv, ax);
    expand1_split_kernel<<<(N_NODES * HIDDEN) / TB, TB, 0, stream>>>(ax, W1, b1, rhi, rlo);

    // conv2..4: GEMM (split-bf16 MFMA) + full-row aggregation
    dim3 ggrid((N_NODES + 127) / 128, 2);
    const int NAGG = (N_NODES + 3) / 4;
    const float* bs[3] = {b2, b3, b4};
    for (int l = 0; l < 3; ++l) {
        mfma_gemm_kernel<<<ggrid, 256, 0, stream>>>(rhi, rlo, whiT + l * 65536,
                                                    wloT + l * 65536, tbuf);
        if (l < 2) {
            agg_full_kernel<0><<<NAGG, 256, 0, stream>>>(tbuf, rowptr, csr_src, csr_norm,
                                                         dinv, bs[l], nullptr, rhi, rlo);
        } else {
            agg_full_kernel<1><<<NAGG, 256, 0, stream>>>(tbuf, rowptr, csr_src, csr_norm,
                                                         dinv, bs[l], hfin, nullptr, nullptr);
        }
    }

    // pooling + head
    bounds_kernel<<<(N_NODES + TB - 1) / TB, TB, 0, stream>>>(batch, gbounds);
    pool_kernel<<<N_GRAPHS, 256, 0, stream>>>(hfin, gbounds, gsum);
    mlp_kernel<<<N_GRAPHS, 128, 0, stream>>>(gsum, lin1_w, lin1_b, lin2_w, lin2_b, out);
}

// Round 5
// 747.734 us; speedup vs baseline: 1.3460x; 1.3460x over previous
//
#include <hip/hip_runtime.h>
#include <hip/hip_bf16.h>

#define N_NODES 50000
#define N_EDGES 800000
#define HIDDEN  256
#define N_GRAPHS 128

typedef short bf16x8 __attribute__((ext_vector_type(8)));
typedef float f32x4 __attribute__((ext_vector_type(4)));

// ---- bf16 split helpers (RNE) ----
__device__ __forceinline__ void bf_split(float x, unsigned short& hi, unsigned short& lo) {
    union { float f; unsigned u; } a; a.f = x;
    unsigned short h16 = (unsigned short)((a.u + 0x7FFFu + ((a.u >> 16) & 1u)) >> 16);
    union { float f; unsigned u; } hf; hf.u = ((unsigned)h16) << 16;
    float res = x - hf.f;
    union { float f; unsigned u; } b; b.f = res;
    unsigned short l16 = (unsigned short)((b.u + 0x7FFFu + ((b.u >> 16) & 1u)) >> 16);
    hi = h16; lo = l16;
}

// ---------------- degree / norm ----------------
__global__ void deg_count_kernel(const int* __restrict__ ei, int* __restrict__ deg) {
    int e = blockIdx.x * blockDim.x + threadIdx.x;
    if (e < N_EDGES) atomicAdd(&deg[ei[N_EDGES + e]], 1);
}

__global__ void dinv_kernel(const int* __restrict__ deg, float* __restrict__ dinv) {
    int i = blockIdx.x * blockDim.x + threadIdx.x;
    if (i < N_NODES) dinv[i] = rsqrtf((float)(deg[i] + 1)); // +1 = self loop
}

// ---------------- hierarchical scan ----------------
__global__ __launch_bounds__(256) void block_scan_kernel(const int* __restrict__ deg,
                                                         int* __restrict__ rowptr,
                                                         int* __restrict__ bsums) {
    __shared__ int s[256];
    int tid = threadIdx.x;
    int i = blockIdx.x * 256 + tid;
    int v = (i < N_NODES) ? deg[i] : 0;
    s[tid] = v;
    __syncthreads();
#pragma unroll
    for (int ofs = 1; ofs < 256; ofs <<= 1) {
        int t = (tid >= ofs) ? s[tid - ofs] : 0;
        __syncthreads();
        s[tid] += t;
        __syncthreads();
    }
    if (i < N_NODES) rowptr[i + 1] = s[tid];
    if (tid == 255) bsums[blockIdx.x] = s[255];
}

__global__ __launch_bounds__(256) void scan_bsums_kernel(int* __restrict__ bsums, int nb) {
    __shared__ int s[256];
    int tid = threadIdx.x;
    int v = (tid < nb) ? bsums[tid] : 0;
    s[tid] = v;
    __syncthreads();
#pragma unroll
    for (int ofs = 1; ofs < 256; ofs <<= 1) {
        int t = (tid >= ofs) ? s[tid - ofs] : 0;
        __syncthreads();
        s[tid] += t;
        __syncthreads();
    }
    if (tid < nb) bsums[tid] = (tid == 0) ? 0 : s[tid - 1];
}

__global__ __launch_bounds__(256) void add_offsets_kernel(int* __restrict__ rowptr,
                                                          const int* __restrict__ bsums) {
    int i = blockIdx.x * 256 + threadIdx.x;
    if (i == 0) rowptr[0] = 0;
    if (i < N_NODES) rowptr[i + 1] += bsums[blockIdx.x];
}

__global__ void fill_csr_kernel(const int* __restrict__ ei, const int* __restrict__ rowptr,
                                int* __restrict__ cursor, const float* __restrict__ dinv,
                                int* __restrict__ csr_src, float* __restrict__ csr_norm) {
    int e = blockIdx.x * blockDim.x + threadIdx.x;
    if (e < N_EDGES) {
        int s = ei[e];
        int d = ei[N_EDGES + e];
        int p = rowptr[d] + atomicAdd(&cursor[d], 1);
        csr_src[p] = s;
        csr_norm[p] = dinv[s] * dinv[d];
    }
}

// ---------------- conv1: aggregate 2-ch x, then expand to split-bf16 ----------------
__global__ void aggx_kernel(const float* __restrict__ x, const int* __restrict__ rowptr,
                            const int* __restrict__ csr_src, const float* __restrict__ csr_norm,
                            const float* __restrict__ dinv, float* __restrict__ ax) {
    int i = blockIdx.x * blockDim.x + threadIdx.x;
    if (i >= N_NODES) return;
    float di = dinv[i];
    float w0 = di * di;
    float a0 = x[2 * i] * w0, a1 = x[2 * i + 1] * w0;
    int e0 = rowptr[i], e1 = rowptr[i + 1];
    for (int p = e0; p < e1; ++p) {
        int s = csr_src[p];
        float w = csr_norm[p];
        a0 += x[2 * s] * w;
        a1 += x[2 * s + 1] * w;
    }
    ax[2 * i] = a0;
    ax[2 * i + 1] = a1;
}

__global__ void expand1_split_kernel(const float* __restrict__ ax, const float* __restrict__ W1,
                                     const float* __restrict__ b1,
                                     unsigned short* __restrict__ rhi,
                                     unsigned short* __restrict__ rlo) {
    int idx = blockIdx.x * blockDim.x + threadIdx.x;
    if (idx >= N_NODES * HIDDEN) return;
    int i = idx >> 8, c = idx & 255;
    float h = ax[2 * i] * W1[c] + ax[2 * i + 1] * W1[HIDDEN + c] + b1[c];
    float r = fmaxf(h, 0.f);
    unsigned short hh, ll;
    bf_split(r, hh, ll);
    rhi[idx] = hh;
    rlo[idx] = ll;
}

// ---------------- W split+transpose (once per call): WT[n][k] bf16 hi/lo ----------------
__global__ void wsplit_kernel(const float* __restrict__ W2, const float* __restrict__ W3,
                              const float* __restrict__ W4,
                              unsigned short* __restrict__ whiT,
                              unsigned short* __restrict__ wloT) {
    int which = blockIdx.y;
    const float* W = (which == 0) ? W2 : ((which == 1) ? W3 : W4);
    unsigned short* hT = whiT + which * 65536;
    unsigned short* lT = wloT + which * 65536;
    int n = blockIdx.x, k = threadIdx.x;
    float v = W[k * 256 + n];
    unsigned short hh, ll;
    bf_split(v, hh, ll);
    hT[n * 256 + k] = hh;
    lT[n * 256 + k] = ll;
}

// ---------------- MFMA GEMM: t = r @ W via 3 split products (R3 structure) ----------------
// t = rhi*Whi + rhi*Wlo + rlo*Whi. 128x128 tile, 4 waves, 64x64/wave, K-chunk 32,
// XOR-swizzled LDS (verified 0-conflict-class in R3; R4's pad-72 variant hit 2.4M conflicts).
__global__ __launch_bounds__(256) void mfma_gemm_kernel(const unsigned short* __restrict__ rhi,
                                                        const unsigned short* __restrict__ rlo,
                                                        const unsigned short* __restrict__ whiT,
                                                        const unsigned short* __restrict__ wloT,
                                                        float* __restrict__ t) {
    __shared__ short As[128][32]; // [row_m][k-window], quad XOR-swizzled
    __shared__ short Bs[128][32]; // [col_n][k-window], quad XOR-swizzled
    int tid = threadIdx.x;
    int row0 = blockIdx.x * 128;
    int col0 = blockIdx.y * 128;
    int lane = tid & 63;
    int wave = tid >> 6;
    int wm = wave >> 1, wn = wave & 1;
    int wq = lane >> 4, lm = lane & 15;

    const unsigned short* Aseg[3] = {rhi, rhi, rlo};
    const unsigned short* Bseg[3] = {whiT, wloT, whiT};

    // staging: thread covers rows (tid>>2) and 64+(tid>>2), quad tid&3 (16B each)
    int arow = tid >> 2;
    int aquad = tid & 3;
    int grow0 = row0 + arow;       if (grow0 >= N_NODES) grow0 = N_NODES - 1;
    int grow1 = row0 + 64 + arow;  if (grow1 >= N_NODES) grow1 = N_NODES - 1;
    int ncol0 = col0 + arow;
    int ncol1 = col0 + 64 + arow;
    int pqs = (aquad ^ (arow & 3)) * 8; // swizzled LDS column (element units)

    f32x4 acc[4][4];
#pragma unroll
    for (int mi = 0; mi < 4; ++mi)
#pragma unroll
        for (int ni = 0; ni < 4; ++ni) acc[mi][ni] = (f32x4)0.f;

    // prefetch chunk 0 (seg 0, kk 0)
    float4 a0 = *(const float4*)(rhi + (size_t)grow0 * 256 + aquad * 8);
    float4 a1 = *(const float4*)(rhi + (size_t)grow1 * 256 + aquad * 8);
    float4 b0 = *(const float4*)(whiT + (size_t)ncol0 * 256 + aquad * 8);
    float4 b1 = *(const float4*)(whiT + (size_t)ncol1 * 256 + aquad * 8);

    int pfr = ((wq ^ (lm & 3)) * 8); // swizzled fragment read column

    for (int cc = 0; cc < 24; ++cc) {
        __syncthreads();
        *(float4*)&As[arow][pqs] = a0;
        *(float4*)&As[64 + arow][pqs] = a1;
        *(float4*)&Bs[arow][pqs] = b0;
        *(float4*)&Bs[64 + arow][pqs] = b1;
        __syncthreads();
        if (cc + 1 < 24) {
            int nc = cc + 1;
            int sg = nc >> 3;
            int kk = (nc & 7) * 32;
            const unsigned short* Ab = Aseg[sg];
            const unsigned short* Bb = Bseg[sg];
            a0 = *(const float4*)(Ab + (size_t)grow0 * 256 + kk + aquad * 8);
            a1 = *(const float4*)(Ab + (size_t)grow1 * 256 + kk + aquad * 8);
            b0 = *(const float4*)(Bb + (size_t)ncol0 * 256 + kk + aquad * 8);
            b1 = *(const float4*)(Bb + (size_t)ncol1 * 256 + kk + aquad * 8);
        }
        bf16x8 af[4], bf[4];
#pragma unroll
        for (int mi = 0; mi < 4; ++mi)
            af[mi] = *(const bf16x8*)&As[wm * 64 + mi * 16 + lm][pfr];
#pragma unroll
        for (int ni = 0; ni < 4; ++ni)
            bf[ni] = *(const bf16x8*)&Bs[wn * 64 + ni * 16 + lm][pfr];
#pragma unroll
        for (int mi = 0; mi < 4; ++mi)
#pragma unroll
            for (int ni = 0; ni < 4; ++ni)
                acc[mi][ni] = __builtin_amdgcn_mfma_f32_16x16x32_bf16(af[mi], bf[ni],
                                                                      acc[mi][ni], 0, 0, 0);
    }

#pragma unroll
    for (int mi = 0; mi < 4; ++mi) {
        int r0 = row0 + wm * 64 + mi * 16 + wq * 4;
#pragma unroll
        for (int ni = 0; ni < 4; ++ni) {
            int col = col0 + wn * 64 + ni * 16 + lm;
#pragma unroll
            for (int r = 0; r < 4; ++r) {
                int rr = r0 + r;
                if (rr < N_NODES) t[(size_t)rr * 256 + col] = acc[mi][ni][r];
            }
        }
    }
}

// ---------------- full-row aggregation, wave per node ----------------
// out[i,:] = sum_e t[src,:]*w + t[i,:]*dinv^2 + b; epilogue: split-relu-bf16 or fp32 (LAST)
template <int LAST>
__global__ __launch_bounds__(256) void agg_full_kernel(const float* __restrict__ t,
                                                       const int* __restrict__ rowptr,
                                                       const int* __restrict__ csr_src,
                                                       const float* __restrict__ csr_norm,
                                                       const float* __restrict__ dinv,
                                                       const float* __restrict__ bias,
                                                       float* __restrict__ hout,
                                                       unsigned short* __restrict__ rhi,
                                                       unsigned short* __restrict__ rlo) {
    int node = blockIdx.x * 4 + (threadIdx.x >> 6);
    if (node >= N_NODES) return;
    int lane = threadIdx.x & 63;
    int c = lane * 4;
    float di = dinv[node];
    float w0 = di * di;
    float4 v = *(const float4*)&t[(size_t)node * HIDDEN + c];
    float4 acc = make_float4(v.x * w0, v.y * w0, v.z * w0, v.w * w0);
    int e0 = rowptr[node], e1 = rowptr[node + 1];
    int p = e0;
    for (; p + 4 <= e1; p += 4) {
        int s0 = csr_src[p + 0], s1 = csr_src[p + 1];
        int s2 = csr_src[p + 2], s3 = csr_src[p + 3];
        float n0 = csr_norm[p + 0], n1 = csr_norm[p + 1];
        float n2 = csr_norm[p + 2], n3 = csr_norm[p + 3];
        float4 u0 = *(const float4*)&t[(size_t)s0 * HIDDEN + c];
        float4 u1 = *(const float4*)&t[(size_t)s1 * HIDDEN + c];
        float4 u2 = *(const float4*)&t[(size_t)s2 * HIDDEN + c];
        float4 u3 = *(const float4*)&t[(size_t)s3 * HIDDEN + c];
        acc.x += u0.x * n0; acc.y += u0.y * n0; acc.z += u0.z * n0; acc.w += u0.w * n0;
        acc.x += u1.x * n1; acc.y += u1.y * n1; acc.z += u1.z * n1; acc.w += u1.w * n1;
        acc.x += u2.x * n2; acc.y += u2.y * n2; acc.z += u2.z * n2; acc.w += u2.w * n2;
        acc.x += u3.x * n3; acc.y += u3.y * n3; acc.z += u3.z * n3; acc.w += u3.w * n3;
    }
    for (; p < e1; ++p) {
        int s = csr_src[p];
        float w = csr_norm[p];
        float4 u = *(const float4*)&t[(size_t)s * HIDDEN + c];
        acc.x += u.x * w; acc.y += u.y * w; acc.z += u.z * w; acc.w += u.w * w;
    }
    float4 b4 = *(const float4*)&bias[c];
    acc.x += b4.x; acc.y += b4.y; acc.z += b4.z; acc.w += b4.w;

    if (LAST) {
        *(float4*)&hout[(size_t)node * HIDDEN + c] = acc;
    } else {
        float r0 = fmaxf(acc.x, 0.f), r1 = fmaxf(acc.y, 0.f);
        float r2 = fmaxf(acc.z, 0.f), r3 = fmaxf(acc.w, 0.f);
        ushort4 h4, l4;
        bf_split(r0, h4.x, l4.x);
        bf_split(r1, h4.y, l4.y);
        bf_split(r2, h4.z, l4.z);
        bf_split(r3, h4.w, l4.w);
        *(ushort4*)&rhi[(size_t)node * HIDDEN + c] = h4;
        *(ushort4*)&rlo[(size_t)node * HIDDEN + c] = l4;
    }
}

// ---------------- pooling ----------------
__global__ void bounds_kernel(const int* __restrict__ batch, int* __restrict__ gbounds) {
    int i = blockIdx.x * blockDim.x + threadIdx.x;
    if (i >= N_NODES) return;
    int bi = batch[i];
    int bprev = (i == 0) ? -1 : batch[i - 1];
    for (int g = bprev + 1; g <= bi; ++g) gbounds[g] = i;
    if (i == N_NODES - 1) {
        for (int g = bi + 1; g <= N_GRAPHS; ++g) gbounds[g] = N_NODES;
    }
}

__global__ __launch_bounds__(256) void pool_kernel(const float* __restrict__ h,
                                                   const int* __restrict__ gbounds,
                                                   float* __restrict__ gsum) {
    int g = blockIdx.x;
    int c = threadIdx.x;
    int s = gbounds[g], e = gbounds[g + 1];
    float acc = 0.f;
    int i = s;
    for (; i + 4 <= e; i += 4) {
        float v0 = h[(size_t)(i + 0) * HIDDEN + c];
        float v1 = h[(size_t)(i + 1) * HIDDEN + c];
        float v2 = h[(size_t)(i + 2) * HIDDEN + c];
        float v3 = h[(size_t)(i + 3) * HIDDEN + c];
        acc += v0 + v1 + v2 + v3;
    }
    for (; i < e; ++i) acc += h[(size_t)i * HIDDEN + c];
    float cnt = (float)(e - s);
    gsum[g * HIDDEN + c] = acc / fmaxf(cnt, 1.f);
}

// ---------------- MLP head ----------------
__global__ __launch_bounds__(128) void mlp_kernel(const float* __restrict__ gsum,
                                                  const float* __restrict__ lin1_w,
                                                  const float* __restrict__ lin1_b,
                                                  const float* __restrict__ lin2_w,
                                                  const float* __restrict__ lin2_b,
                                                  float* __restrict__ out) {
    __shared__ float grow[HIDDEN];
    __shared__ float red[2];
    int g = blockIdx.x, j = threadIdx.x;
    grow[j] = gsum[g * HIDDEN + j];
    grow[j + 128] = gsum[g * HIDDEN + j + 128];
    __syncthreads();
    float acc = lin1_b[j];
    for (int k = 0; k < HIDDEN; ++k) acc += grow[k] * lin1_w[k * 128 + j];
    acc = fmaxf(acc, 0.f);
    float v = acc * lin2_w[j];
#pragma unroll
    for (int ofs = 32; ofs > 0; ofs >>= 1) v += __shfl_down(v, ofs, 64);
    if ((j & 63) == 0) red[j >> 6] = v;
    __syncthreads();
    if (j == 0) out[g] = red[0] + red[1] + lin2_b[0];
}

// ---------------- launch ----------------
extern "C" void kernel_launch(void* const* d_in, const int* in_sizes, int n_in,
                              void* d_out, int out_size, void* d_ws, size_t ws_size,
                              hipStream_t stream) {
    const float* x      = (const float*)d_in[0];
    const int*   ei     = (const int*)d_in[1];
    const int*   batch  = (const int*)d_in[2];
    const float* W1     = (const float*)d_in[3];
    const float* b1     = (const float*)d_in[4];
    const float* W2     = (const float*)d_in[5];
    const float* b2     = (const float*)d_in[6];
    const float* W3     = (const float*)d_in[7];
    const float* b3     = (const float*)d_in[8];
    const float* W4     = (const float*)d_in[9];
    const float* b4     = (const float*)d_in[10];
    const float* lin1_w = (const float*)d_in[11];
    const float* lin1_b = (const float*)d_in[12];
    const float* lin2_w = (const float*)d_in[13];
    const float* lin2_b = (const float*)d_in[14];
    float* out = (float*)d_out;

    char* ws = (char*)d_ws;
    size_t off = 0;
    auto alloc = [&](size_t bytes) -> void* {
        void* p = ws + off;
        off += (bytes + 255) & ~(size_t)255;
        return p;
    };
    float*          tbuf   = (float*)alloc((size_t)N_NODES * HIDDEN * 4);   // 51.2 MB
    void*           rgn    = alloc((size_t)N_NODES * HIDDEN * 4);           // 51.2 MB (rhi+rlo | hfin)
    unsigned short* rhi    = (unsigned short*)rgn;
    unsigned short* rlo    = rhi + (size_t)N_NODES * HIDDEN;
    float*          hfin   = (float*)rgn;
    float* csr_norm = (float*)alloc((size_t)N_EDGES * 4);
    int*   csr_src  = (int*)alloc((size_t)N_EDGES * 4);
    int*   rowptr   = (int*)alloc((size_t)(N_NODES + 1) * 4);
    int*   deg      = (int*)alloc((size_t)N_NODES * 4);
    int*   cursor   = (int*)alloc((size_t)N_NODES * 4);
    float* dinv     = (float*)alloc((size_t)N_NODES * 4);
    float* ax       = (float*)alloc((size_t)N_NODES * 2 * 4);
    float* gsum     = (float*)alloc((size_t)N_GRAPHS * HIDDEN * 4);
    int*   gbounds  = (int*)alloc((size_t)(N_GRAPHS + 1) * 4);
    int*   bsums    = (int*)alloc((size_t)256 * 4);
    unsigned short* whiT = (unsigned short*)alloc((size_t)3 * 65536 * 2);
    unsigned short* wloT = (unsigned short*)alloc((size_t)3 * 65536 * 2);

    hipMemsetAsync(deg, 0, (size_t)N_NODES * 4, stream);
    hipMemsetAsync(cursor, 0, (size_t)N_NODES * 4, stream);

    const int TB = 256;
    const int NBLK = (N_NODES + 255) / 256;
    deg_count_kernel<<<(N_EDGES + TB - 1) / TB, TB, 0, stream>>>(ei, deg);
    dinv_kernel<<<(N_NODES + TB - 1) / TB, TB, 0, stream>>>(deg, dinv);
    block_scan_kernel<<<NBLK, 256, 0, stream>>>(deg, rowptr, bsums);
    scan_bsums_kernel<<<1, 256, 0, stream>>>(bsums, NBLK);
    add_offsets_kernel<<<NBLK, 256, 0, stream>>>(rowptr, bsums);
    fill_csr_kernel<<<(N_EDGES + TB - 1) / TB, TB, 0, stream>>>(ei, rowptr, cursor, dinv,
                                                                csr_src, csr_norm);
    wsplit_kernel<<<dim3(256, 3), 256, 0, stream>>>(W2, W3, W4, whiT, wloT);

    // conv1: (A x) W1 + b1 -> relu -> split bf16
    aggx_kernel<<<(N_NODES + TB - 1) / TB, TB, 0, stream>>>(x, rowptr, csr_src, csr_norm, dinv, ax);
    expand1_split_kernel<<<(N_NODES * HIDDEN) / TB, TB, 0, stream>>>(ax, W1, b1, rhi, rlo);

    // conv2..4: GEMM (split-bf16 MFMA) + full-row aggregation
    dim3 ggrid((N_NODES + 127) / 128, 2);
    const int NAGG = (N_NODES + 3) / 4;
    const float* bs[3] = {b2, b3, b4};
    for (int l = 0; l < 3; ++l) {
        mfma_gemm_kernel<<<ggrid, 256, 0, stream>>>(rhi, rlo, whiT + l * 65536,
                                                    wloT + l * 65536, tbuf);
        if (l < 2) {
            agg_full_kernel<0><<<NAGG, 256, 0, stream>>>(tbuf, rowptr, csr_src, csr_norm,
                                                         dinv, bs[l], nullptr, rhi, rlo);
        } else {
            agg_full_kernel<1><<<NAGG, 256, 0, stream>>>(tbuf, rowptr, csr_src, csr_norm,
                                                         dinv, bs[l], hfin, nullptr, nullptr);
        }
    }

    // pooling + head
    bounds_kernel<<<(N_NODES + TB - 1) / TB, TB, 0, stream>>>(batch, gbounds);
    pool_kernel<<<N_GRAPHS, 256, 0, stream>>>(hfin, gbounds, gsum);
    mlp_kernel<<<N_GRAPHS, 128, 0, stream>>>(gsum, lin1_w, lin1_b, lin2_w, lin2_b, out);
}

// Round 6
// 572.899 us; speedup vs baseline: 1.7567x; 1.3052x over previous
//
#include <hip/hip_runtime.h>
#include <hip/hip_bf16.h>
#include <hip/hip_fp16.h>

#define N_NODES 50000
#define N_EDGES 800000
#define HIDDEN  256
#define N_GRAPHS 128

typedef short bf16x8 __attribute__((ext_vector_type(8)));
typedef float f32x4 __attribute__((ext_vector_type(4)));

// ---- bf16 split helpers (RNE) ----
__device__ __forceinline__ void bf_split(float x, unsigned short& hi, unsigned short& lo) {
    union { float f; unsigned u; } a; a.f = x;
    unsigned short h16 = (unsigned short)((a.u + 0x7FFFu + ((a.u >> 16) & 1u)) >> 16);
    union { float f; unsigned u; } hf; hf.u = ((unsigned)h16) << 16;
    float res = x - hf.f;
    union { float f; unsigned u; } b; b.f = res;
    unsigned short l16 = (unsigned short)((b.u + 0x7FFFu + ((b.u >> 16) & 1u)) >> 16);
    hi = h16; lo = l16;
}

// ---- fp16x4 row-chunk load + convert ----
__device__ __forceinline__ float4 h8load(const __half* p) {
    uint2 raw = *(const uint2*)p;
    __half2 h01 = *(__half2*)&raw.x;
    __half2 h23 = *(__half2*)&raw.y;
    float2 f01 = __half22float2(h01);
    float2 f23 = __half22float2(h23);
    return make_float4(f01.x, f01.y, f23.x, f23.y);
}

// ---------------- degree / norm ----------------
__global__ void deg_count_kernel(const int* __restrict__ ei, int* __restrict__ deg) {
    int e = blockIdx.x * blockDim.x + threadIdx.x;
    if (e < N_EDGES) atomicAdd(&deg[ei[N_EDGES + e]], 1);
}

__global__ void dinv_kernel(const int* __restrict__ deg, float* __restrict__ dinv) {
    int i = blockIdx.x * blockDim.x + threadIdx.x;
    if (i < N_NODES) dinv[i] = rsqrtf((float)(deg[i] + 1)); // +1 = self loop
}

// ---------------- hierarchical scan ----------------
__global__ __launch_bounds__(256) void block_scan_kernel(const int* __restrict__ deg,
                                                         int* __restrict__ rowptr,
                                                         int* __restrict__ bsums) {
    __shared__ int s[256];
    int tid = threadIdx.x;
    int i = blockIdx.x * 256 + tid;
    int v = (i < N_NODES) ? deg[i] : 0;
    s[tid] = v;
    __syncthreads();
#pragma unroll
    for (int ofs = 1; ofs < 256; ofs <<= 1) {
        int t = (tid >= ofs) ? s[tid - ofs] : 0;
        __syncthreads();
        s[tid] += t;
        __syncthreads();
    }
    if (i < N_NODES) rowptr[i + 1] = s[tid];
    if (tid == 255) bsums[blockIdx.x] = s[255];
}

__global__ __launch_bounds__(256) void scan_bsums_kernel(int* __restrict__ bsums, int nb) {
    __shared__ int s[256];
    int tid = threadIdx.x;
    int v = (tid < nb) ? bsums[tid] : 0;
    s[tid] = v;
    __syncthreads();
#pragma unroll
    for (int ofs = 1; ofs < 256; ofs <<= 1) {
        int t = (tid >= ofs) ? s[tid - ofs] : 0;
        __syncthreads();
        s[tid] += t;
        __syncthreads();
    }
    if (tid < nb) bsums[tid] = (tid == 0) ? 0 : s[tid - 1];
}

__global__ __launch_bounds__(256) void add_offsets_kernel(int* __restrict__ rowptr,
                                                          const int* __restrict__ bsums) {
    int i = blockIdx.x * 256 + threadIdx.x;
    if (i == 0) rowptr[0] = 0;
    if (i < N_NODES) rowptr[i + 1] += bsums[blockIdx.x];
}

__global__ void fill_csr_kernel(const int* __restrict__ ei, const int* __restrict__ rowptr,
                                int* __restrict__ cursor, const float* __restrict__ dinv,
                                int* __restrict__ csr_src, float* __restrict__ csr_norm) {
    int e = blockIdx.x * blockDim.x + threadIdx.x;
    if (e < N_EDGES) {
        int s = ei[e];
        int d = ei[N_EDGES + e];
        int p = rowptr[d] + atomicAdd(&cursor[d], 1);
        csr_src[p] = s;
        csr_norm[p] = dinv[s] * dinv[d];
    }
}

// ---------------- conv1: aggregate 2-ch x, then expand to split-bf16 ----------------
__global__ void aggx_kernel(const float* __restrict__ x, const int* __restrict__ rowptr,
                            const int* __restrict__ csr_src, const float* __restrict__ csr_norm,
                            const float* __restrict__ dinv, float* __restrict__ ax) {
    int i = blockIdx.x * blockDim.x + threadIdx.x;
    if (i >= N_NODES) return;
    float di = dinv[i];
    float w0 = di * di;
    float a0 = x[2 * i] * w0, a1 = x[2 * i + 1] * w0;
    int e0 = rowptr[i], e1 = rowptr[i + 1];
    for (int p = e0; p < e1; ++p) {
        int s = csr_src[p];
        float w = csr_norm[p];
        a0 += x[2 * s] * w;
        a1 += x[2 * s + 1] * w;
    }
    ax[2 * i] = a0;
    ax[2 * i + 1] = a1;
}

__global__ void expand1_split_kernel(const float* __restrict__ ax, const float* __restrict__ W1,
                                     const float* __restrict__ b1,
                                     unsigned short* __restrict__ rhi,
                                     unsigned short* __restrict__ rlo) {
    int idx = blockIdx.x * blockDim.x + threadIdx.x;
    if (idx >= N_NODES * HIDDEN) return;
    int i = idx >> 8, c = idx & 255;
    float h = ax[2 * i] * W1[c] + ax[2 * i + 1] * W1[HIDDEN + c] + b1[c];
    float r = fmaxf(h, 0.f);
    unsigned short hh, ll;
    bf_split(r, hh, ll);
    rhi[idx] = hh;
    rlo[idx] = ll;
}

// ---------------- W split+transpose (once per call): WT[n][k] bf16 hi/lo ----------------
__global__ void wsplit_kernel(const float* __restrict__ W2, const float* __restrict__ W3,
                              const float* __restrict__ W4,
                              unsigned short* __restrict__ whiT,
                              unsigned short* __restrict__ wloT) {
    int which = blockIdx.y;
    const float* W = (which == 0) ? W2 : ((which == 1) ? W3 : W4);
    unsigned short* hT = whiT + which * 65536;
    unsigned short* lT = wloT + which * 65536;
    int n = blockIdx.x, k = threadIdx.x;
    float v = W[k * 256 + n];
    unsigned short hh, ll;
    bf_split(v, hh, ll);
    hT[n * 256 + k] = hh;
    lT[n * 256 + k] = ll;
}

// ---------------- MFMA GEMM: t = r @ W via 3 split products, fp16 output ----------------
// t = rhi*Whi + rhi*Wlo + rlo*Whi. 128x128 tile, 4 waves, 64x64/wave, K-chunk 32,
// XOR-swizzled LDS staging (R3 structure, verified low-conflict).
// Epilogue: fp32 acc -> fp16, staged via LDS tile for coalesced 512B-row stores.
__global__ __launch_bounds__(256) void mfma_gemm_kernel(const unsigned short* __restrict__ rhi,
                                                        const unsigned short* __restrict__ rlo,
                                                        const unsigned short* __restrict__ whiT,
                                                        const unsigned short* __restrict__ wloT,
                                                        __half* __restrict__ t) {
    __shared__ short As[128][32]; // [row_m][k-window], quad XOR-swizzled
    __shared__ short Bs[128][32]; // [col_n][k-window], quad XOR-swizzled
    __shared__ __half Cs[128][140]; // output staging; pad 140 -> <=2-way write aliasing
    int tid = threadIdx.x;
    int row0 = blockIdx.x * 128;
    int col0 = blockIdx.y * 128;
    int lane = tid & 63;
    int wave = tid >> 6;
    int wm = wave >> 1, wn = wave & 1;
    int wq = lane >> 4, lm = lane & 15;

    const unsigned short* Aseg[3] = {rhi, rhi, rlo};
    const unsigned short* Bseg[3] = {whiT, wloT, whiT};

    // staging: thread covers rows (tid>>2) and 64+(tid>>2), quad tid&3 (16B each)
    int arow = tid >> 2;
    int aquad = tid & 3;
    int grow0 = row0 + arow;       if (grow0 >= N_NODES) grow0 = N_NODES - 1;
    int grow1 = row0 + 64 + arow;  if (grow1 >= N_NODES) grow1 = N_NODES - 1;
    int ncol0 = col0 + arow;
    int ncol1 = col0 + 64 + arow;
    int pqs = (aquad ^ (arow & 3)) * 8; // swizzled LDS column (element units)

    f32x4 acc[4][4];
#pragma unroll
    for (int mi = 0; mi < 4; ++mi)
#pragma unroll
        for (int ni = 0; ni < 4; ++ni) acc[mi][ni] = (f32x4)0.f;

    // prefetch chunk 0 (seg 0, kk 0)
    float4 a0 = *(const float4*)(rhi + (size_t)grow0 * 256 + aquad * 8);
    float4 a1 = *(const float4*)(rhi + (size_t)grow1 * 256 + aquad * 8);
    float4 b0 = *(const float4*)(whiT + (size_t)ncol0 * 256 + aquad * 8);
    float4 b1 = *(const float4*)(whiT + (size_t)ncol1 * 256 + aquad * 8);

    int pfr = ((wq ^ (lm & 3)) * 8); // swizzled fragment read column

    for (int cc = 0; cc < 24; ++cc) {
        __syncthreads();
        *(float4*)&As[arow][pqs] = a0;
        *(float4*)&As[64 + arow][pqs] = a1;
        *(float4*)&Bs[arow][pqs] = b0;
        *(float4*)&Bs[64 + arow][pqs] = b1;
        __syncthreads();
        if (cc + 1 < 24) {
            int nc = cc + 1;
            int sg = nc >> 3;
            int kk = (nc & 7) * 32;
            const unsigned short* Ab = Aseg[sg];
            const unsigned short* Bb = Bseg[sg];
            a0 = *(const float4*)(Ab + (size_t)grow0 * 256 + kk + aquad * 8);
            a1 = *(const float4*)(Ab + (size_t)grow1 * 256 + kk + aquad * 8);
            b0 = *(const float4*)(Bb + (size_t)ncol0 * 256 + kk + aquad * 8);
            b1 = *(const float4*)(Bb + (size_t)ncol1 * 256 + kk + aquad * 8);
        }
        bf16x8 af[4], bf[4];
#pragma unroll
        for (int mi = 0; mi < 4; ++mi)
            af[mi] = *(const bf16x8*)&As[wm * 64 + mi * 16 + lm][pfr];
#pragma unroll
        for (int ni = 0; ni < 4; ++ni)
            bf[ni] = *(const bf16x8*)&Bs[wn * 64 + ni * 16 + lm][pfr];
#pragma unroll
        for (int mi = 0; mi < 4; ++mi)
#pragma unroll
            for (int ni = 0; ni < 4; ++ni)
                acc[mi][ni] = __builtin_amdgcn_mfma_f32_16x16x32_bf16(af[mi], bf[ni],
                                                                      acc[mi][ni], 0, 0, 0);
    }

    // epilogue: acc -> fp16 tile in LDS -> coalesced row stores
    __syncthreads();
#pragma unroll
    for (int mi = 0; mi < 4; ++mi) {
        int rb = wm * 64 + mi * 16 + wq * 4;
#pragma unroll
        for (int ni = 0; ni < 4; ++ni) {
            int cb = wn * 64 + ni * 16 + lm;
#pragma unroll
            for (int r = 0; r < 4; ++r)
                Cs[rb + r][cb] = __float2half(acc[mi][ni][r]);
        }
    }
    __syncthreads();
#pragma unroll
    for (int pass = 0; pass < 16; ++pass) {
        int row = pass * 8 + (tid >> 5);
        int gr = row0 + row;
        int chunk = tid & 31;
        if (gr < N_NODES)
            *(uint2*)(t + (size_t)gr * 256 + col0 + chunk * 4) =
                *(const uint2*)&Cs[row][chunk * 4];
    }
}

// ---------------- full-row aggregation, wave per node, fp16 gather ----------------
// out[i,:] = sum_e t[src,:]*w + t[i,:]*dinv^2 + b; epilogue: split-relu-bf16 or fp32 (LAST)
template <int LAST>
__global__ __launch_bounds__(256) void agg_full_kernel(const __half* __restrict__ t,
                                                       const int* __restrict__ rowptr,
                                                       const int* __restrict__ csr_src,
                                                       const float* __restrict__ csr_norm,
                                                       const float* __restrict__ dinv,
                                                       const float* __restrict__ bias,
                                                       float* __restrict__ hout,
                                                       unsigned short* __restrict__ rhi,
                                                       unsigned short* __restrict__ rlo) {
    int node = blockIdx.x * 4 + (threadIdx.x >> 6);
    if (node >= N_NODES) return;
    int lane = threadIdx.x & 63;
    int c = lane * 4;
    float di = dinv[node];
    float w0 = di * di;
    float4 v = h8load(t + (size_t)node * HIDDEN + c);
    float4 acc = make_float4(v.x * w0, v.y * w0, v.z * w0, v.w * w0);
    int e0 = rowptr[node], e1 = rowptr[node + 1];
    int p = e0;
    for (; p + 4 <= e1; p += 4) {
        int s0 = csr_src[p + 0], s1 = csr_src[p + 1];
        int s2 = csr_src[p + 2], s3 = csr_src[p + 3];
        float n0 = csr_norm[p + 0], n1 = csr_norm[p + 1];
        float n2 = csr_norm[p + 2], n3 = csr_norm[p + 3];
        float4 u0 = h8load(t + (size_t)s0 * HIDDEN + c);
        float4 u1 = h8load(t + (size_t)s1 * HIDDEN + c);
        float4 u2 = h8load(t + (size_t)s2 * HIDDEN + c);
        float4 u3 = h8load(t + (size_t)s3 * HIDDEN + c);
        acc.x += u0.x * n0; acc.y += u0.y * n0; acc.z += u0.z * n0; acc.w += u0.w * n0;
        acc.x += u1.x * n1; acc.y += u1.y * n1; acc.z += u1.z * n1; acc.w += u1.w * n1;
        acc.x += u2.x * n2; acc.y += u2.y * n2; acc.z += u2.z * n2; acc.w += u2.w * n2;
        acc.x += u3.x * n3; acc.y += u3.y * n3; acc.z += u3.z * n3; acc.w += u3.w * n3;
    }
    for (; p < e1; ++p) {
        int s = csr_src[p];
        float w = csr_norm[p];
        float4 u = h8load(t + (size_t)s * HIDDEN + c);
        acc.x += u.x * w; acc.y += u.y * w; acc.z += u.z * w; acc.w += u.w * w;
    }
    float4 b4 = *(const float4*)&bias[c];
    acc.x += b4.x; acc.y += b4.y; acc.z += b4.z; acc.w += b4.w;

    if (LAST) {
        *(float4*)&hout[(size_t)node * HIDDEN + c] = acc;
    } else {
        float r0 = fmaxf(acc.x, 0.f), r1 = fmaxf(acc.y, 0.f);
        float r2 = fmaxf(acc.z, 0.f), r3 = fmaxf(acc.w, 0.f);
        ushort4 h4, l4;
        bf_split(r0, h4.x, l4.x);
        bf_split(r1, h4.y, l4.y);
        bf_split(r2, h4.z, l4.z);
        bf_split(r3, h4.w, l4.w);
        *(ushort4*)&rhi[(size_t)node * HIDDEN + c] = h4;
        *(ushort4*)&rlo[(size_t)node * HIDDEN + c] = l4;
    }
}

// ---------------- pooling ----------------
__global__ void bounds_kernel(const int* __restrict__ batch, int* __restrict__ gbounds) {
    int i = blockIdx.x * blockDim.x + threadIdx.x;
    if (i >= N_NODES) return;
    int bi = batch[i];
    int bprev = (i == 0) ? -1 : batch[i - 1];
    for (int g = bprev + 1; g <= bi; ++g) gbounds[g] = i;
    if (i == N_NODES - 1) {
        for (int g = bi + 1; g <= N_GRAPHS; ++g) gbounds[g] = N_NODES;
    }
}

__global__ __launch_bounds__(256) void pool_kernel(const float* __restrict__ h,
                                                   const int* __restrict__ gbounds,
                                                   float* __restrict__ gsum) {
    int g = blockIdx.x;
    int c = threadIdx.x;
    int s = gbounds[g], e = gbounds[g + 1];
    float acc = 0.f;
    int i = s;
    for (; i + 4 <= e; i += 4) {
        float v0 = h[(size_t)(i + 0) * HIDDEN + c];
        float v1 = h[(size_t)(i + 1) * HIDDEN + c];
        float v2 = h[(size_t)(i + 2) * HIDDEN + c];
        float v3 = h[(size_t)(i + 3) * HIDDEN + c];
        acc += v0 + v1 + v2 + v3;
    }
    for (; i < e; ++i) acc += h[(size_t)i * HIDDEN + c];
    float cnt = (float)(e - s);
    gsum[g * HIDDEN + c] = acc / fmaxf(cnt, 1.f);
}

// ---------------- MLP head ----------------
__global__ __launch_bounds__(128) void mlp_kernel(const float* __restrict__ gsum,
                                                  const float* __restrict__ lin1_w,
                                                  const float* __restrict__ lin1_b,
                                                  const float* __restrict__ lin2_w,
                                                  const float* __restrict__ lin2_b,
                                                  float* __restrict__ out) {
    __shared__ float grow[HIDDEN];
    __shared__ float red[2];
    int g = blockIdx.x, j = threadIdx.x;
    grow[j] = gsum[g * HIDDEN + j];
    grow[j + 128] = gsum[g * HIDDEN + j + 128];
    __syncthreads();
    float acc = lin1_b[j];
    for (int k = 0; k < HIDDEN; ++k) acc += grow[k] * lin1_w[k * 128 + j];
    acc = fmaxf(acc, 0.f);
    float v = acc * lin2_w[j];
#pragma unroll
    for (int ofs = 32; ofs > 0; ofs >>= 1) v += __shfl_down(v, ofs, 64);
    if ((j & 63) == 0) red[j >> 6] = v;
    __syncthreads();
    if (j == 0) out[g] = red[0] + red[1] + lin2_b[0];
}

// ---------------- launch ----------------
extern "C" void kernel_launch(void* const* d_in, const int* in_sizes, int n_in,
                              void* d_out, int out_size, void* d_ws, size_t ws_size,
                              hipStream_t stream) {
    const float* x      = (const float*)d_in[0];
    const int*   ei     = (const int*)d_in[1];
    const int*   batch  = (const int*)d_in[2];
    const float* W1     = (const float*)d_in[3];
    const float* b1     = (const float*)d_in[4];
    const float* W2     = (const float*)d_in[5];
    const float* b2     = (const float*)d_in[6];
    const float* W3     = (const float*)d_in[7];
    const float* b3     = (const float*)d_in[8];
    const float* W4     = (const float*)d_in[9];
    const float* b4     = (const float*)d_in[10];
    const float* lin1_w = (const float*)d_in[11];
    const float* lin1_b = (const float*)d_in[12];
    const float* lin2_w = (const float*)d_in[13];
    const float* lin2_b = (const float*)d_in[14];
    float* out = (float*)d_out;

    char* ws = (char*)d_ws;
    size_t off = 0;
    auto alloc = [&](size_t bytes) -> void* {
        void* p = ws + off;
        off += (bytes + 255) & ~(size_t)255;
        return p;
    };
    __half*         tbuf   = (__half*)alloc((size_t)N_NODES * HIDDEN * 2);  // 25.6 MB fp16
    void*           rgn    = alloc((size_t)N_NODES * HIDDEN * 4);           // 51.2 MB (rhi+rlo | hfin)
    unsigned short* rhi    = (unsigned short*)rgn;
    unsigned short* rlo    = rhi + (size_t)N_NODES * HIDDEN;
    float*          hfin   = (float*)rgn;
    float* csr_norm = (float*)alloc((size_t)N_EDGES * 4);
    int*   csr_src  = (int*)alloc((size_t)N_EDGES * 4);
    int*   rowptr   = (int*)alloc((size_t)(N_NODES + 1) * 4);
    int*   deg      = (int*)alloc((size_t)N_NODES * 4);
    int*   cursor   = (int*)alloc((size_t)N_NODES * 4);
    float* dinv     = (float*)alloc((size_t)N_NODES * 4);
    float* ax       = (float*)alloc((size_t)N_NODES * 2 * 4);
    float* gsum     = (float*)alloc((size_t)N_GRAPHS * HIDDEN * 4);
    int*   gbounds  = (int*)alloc((size_t)(N_GRAPHS + 1) * 4);
    int*   bsums    = (int*)alloc((size_t)256 * 4);
    unsigned short* whiT = (unsigned short*)alloc((size_t)3 * 65536 * 2);
    unsigned short* wloT = (unsigned short*)alloc((size_t)3 * 65536 * 2);

    hipMemsetAsync(deg, 0, (size_t)N_NODES * 4, stream);
    hipMemsetAsync(cursor, 0, (size_t)N_NODES * 4, stream);

    const int TB = 256;
    const int NBLK = (N_NODES + 255) / 256;
    deg_count_kernel<<<(N_EDGES + TB - 1) / TB, TB, 0, stream>>>(ei, deg);
    dinv_kernel<<<(N_NODES + TB - 1) / TB, TB, 0, stream>>>(deg, dinv);
    block_scan_kernel<<<NBLK, 256, 0, stream>>>(deg, rowptr, bsums);
    scan_bsums_kernel<<<1, 256, 0, stream>>>(bsums, NBLK);
    add_offsets_kernel<<<NBLK, 256, 0, stream>>>(rowptr, bsums);
    fill_csr_kernel<<<(N_EDGES + TB - 1) / TB, TB, 0, stream>>>(ei, rowptr, cursor, dinv,
                                                                csr_src, csr_norm);
    wsplit_kernel<<<dim3(256, 3), 256, 0, stream>>>(W2, W3, W4, whiT, wloT);

    // conv1: (A x) W1 + b1 -> relu -> split bf16
    aggx_kernel<<<(N_NODES + TB - 1) / TB, TB, 0, stream>>>(x, rowptr, csr_src, csr_norm, dinv, ax);
    expand1_split_kernel<<<(N_NODES * HIDDEN) / TB, TB, 0, stream>>>(ax, W1, b1, rhi, rlo);

    // conv2..4: GEMM (split-bf16 MFMA, fp16 out) + full-row fp16-gather aggregation
    dim3 ggrid((N_NODES + 127) / 128, 2);
    const int NAGG = (N_NODES + 3) / 4;
    const float* bs[3] = {b2, b3, b4};
    for (int l = 0; l < 3; ++l) {
        mfma_gemm_kernel<<<ggrid, 256, 0, stream>>>(rhi, rlo, whiT + l * 65536,
                                                    wloT + l * 65536, tbuf);
        if (l < 2) {
            agg_full_kernel<0><<<NAGG, 256, 0, stream>>>(tbuf, rowptr, csr_src, csr_norm,
                                                         dinv, bs[l], nullptr, rhi, rlo);
        } else {
            agg_full_kernel<1><<<NAGG, 256, 0, stream>>>(tbuf, rowptr, csr_src, csr_norm,
                                                         dinv, bs[l], hfin, nullptr, nullptr);
        }
    }

    // pooling + head
    bounds_kernel<<<(N_NODES + TB - 1) / TB, TB, 0, stream>>>(batch, gbounds);
    pool_kernel<<<N_GRAPHS, 256, 0, stream>>>(hfin, gbounds, gsum);
    mlp_kernel<<<N_GRAPHS, 128, 0, stream>>>(gsum, lin1_w, lin1_b, lin2_w, lin2_b, out);
}

// Round 7
// 545.148 us; speedup vs baseline: 1.8461x; 1.0509x over previous
//
#include <hip/hip_runtime.h>
#include <hip/hip_bf16.h>
#include <hip/hip_fp16.h>

#define N_NODES 50000
#define N_EDGES 800000
#define HIDDEN  256
#define N_GRAPHS 128

typedef short bf16x8 __attribute__((ext_vector_type(8)));
typedef float f32x4 __attribute__((ext_vector_type(4)));

// ---- bf16 split helpers (RNE) ----
__device__ __forceinline__ void bf_split(float x, unsigned short& hi, unsigned short& lo) {
    union { float f; unsigned u; } a; a.f = x;
    unsigned short h16 = (unsigned short)((a.u + 0x7FFFu + ((a.u >> 16) & 1u)) >> 16);
    union { float f; unsigned u; } hf; hf.u = ((unsigned)h16) << 16;
    float res = x - hf.f;
    union { float f; unsigned u; } b; b.f = res;
    unsigned short l16 = (unsigned short)((b.u + 0x7FFFu + ((b.u >> 16) & 1u)) >> 16);
    hi = h16; lo = l16;
}

// ---- fp16x4 row-chunk load + convert ----
__device__ __forceinline__ float4 h8load(const __half* p) {
    uint2 raw = *(const uint2*)p;
    __half2 h01 = *(__half2*)&raw.x;
    __half2 h23 = *(__half2*)&raw.y;
    float2 f01 = __half22float2(h01);
    float2 f23 = __half22float2(h23);
    return make_float4(f01.x, f01.y, f23.x, f23.y);
}

// ---------------- degree / norm ----------------
__global__ void deg_count_kernel(const int* __restrict__ ei, int* __restrict__ deg) {
    int e = blockIdx.x * blockDim.x + threadIdx.x;
    if (e < N_EDGES) atomicAdd(&deg[ei[N_EDGES + e]], 1);
}

// ---------------- hierarchical scan (also emits dinv) ----------------
__global__ __launch_bounds__(256) void block_scan_kernel(const int* __restrict__ deg,
                                                         int* __restrict__ rowptr,
                                                         int* __restrict__ bsums,
                                                         float* __restrict__ dinv) {
    __shared__ int s[256];
    int tid = threadIdx.x;
    int i = blockIdx.x * 256 + tid;
    int v = (i < N_NODES) ? deg[i] : 0;
    if (i < N_NODES) dinv[i] = rsqrtf((float)(v + 1)); // +1 = self loop
    s[tid] = v;
    __syncthreads();
#pragma unroll
    for (int ofs = 1; ofs < 256; ofs <<= 1) {
        int t = (tid >= ofs) ? s[tid - ofs] : 0;
        __syncthreads();
        s[tid] += t;
        __syncthreads();
    }
    if (i < N_NODES) rowptr[i + 1] = s[tid];
    if (tid == 255) bsums[blockIdx.x] = s[255];
}

__global__ __launch_bounds__(256) void scan_bsums_kernel(int* __restrict__ bsums, int nb) {
    __shared__ int s[256];
    int tid = threadIdx.x;
    int v = (tid < nb) ? bsums[tid] : 0;
    s[tid] = v;
    __syncthreads();
#pragma unroll
    for (int ofs = 1; ofs < 256; ofs <<= 1) {
        int t = (tid >= ofs) ? s[tid - ofs] : 0;
        __syncthreads();
        s[tid] += t;
        __syncthreads();
    }
    if (tid < nb) bsums[tid] = (tid == 0) ? 0 : s[tid - 1];
}

__global__ __launch_bounds__(256) void add_offsets_kernel(int* __restrict__ rowptr,
                                                          const int* __restrict__ bsums) {
    int i = blockIdx.x * 256 + threadIdx.x;
    if (i == 0) rowptr[0] = 0;
    if (i < N_NODES) rowptr[i + 1] += bsums[blockIdx.x];
}

__global__ void fill_csr_kernel(const int* __restrict__ ei, const int* __restrict__ rowptr,
                                int* __restrict__ cursor, const float* __restrict__ dinv,
                                int* __restrict__ csr_src, float* __restrict__ csr_norm) {
    int e = blockIdx.x * blockDim.x + threadIdx.x;
    if (e < N_EDGES) {
        int s = ei[e];
        int d = ei[N_EDGES + e];
        int p = rowptr[d] + atomicAdd(&cursor[d], 1);
        csr_src[p] = s;
        csr_norm[p] = dinv[s] * dinv[d];
    }
}

// ---------------- conv1: aggregate 2-ch x, then expand to split-bf16 ----------------
__global__ void aggx_kernel(const float* __restrict__ x, const int* __restrict__ rowptr,
                            const int* __restrict__ csr_src, const float* __restrict__ csr_norm,
                            const float* __restrict__ dinv, float* __restrict__ ax) {
    int i = blockIdx.x * blockDim.x + threadIdx.x;
    if (i >= N_NODES) return;
    float di = dinv[i];
    float w0 = di * di;
    float2 xi = *(const float2*)&x[2 * i];
    float a0 = xi.x * w0, a1 = xi.y * w0;
    int e0 = rowptr[i], e1 = rowptr[i + 1];
    int p = e0;
    for (; p + 4 <= e1; p += 4) {
        int s0 = csr_src[p + 0], s1 = csr_src[p + 1];
        int s2 = csr_src[p + 2], s3 = csr_src[p + 3];
        float n0 = csr_norm[p + 0], n1 = csr_norm[p + 1];
        float n2 = csr_norm[p + 2], n3 = csr_norm[p + 3];
        float2 u0 = *(const float2*)&x[2 * s0];
        float2 u1 = *(const float2*)&x[2 * s1];
        float2 u2 = *(const float2*)&x[2 * s2];
        float2 u3 = *(const float2*)&x[2 * s3];
        a0 += u0.x * n0 + u1.x * n1 + u2.x * n2 + u3.x * n3;
        a1 += u0.y * n0 + u1.y * n1 + u2.y * n2 + u3.y * n3;
    }
    for (; p < e1; ++p) {
        int s = csr_src[p];
        float w = csr_norm[p];
        float2 u = *(const float2*)&x[2 * s];
        a0 += u.x * w;
        a1 += u.y * w;
    }
    ax[2 * i] = a0;
    ax[2 * i + 1] = a1;
}

__global__ void expand1_split_kernel(const float* __restrict__ ax, const float* __restrict__ W1,
                                     const float* __restrict__ b1,
                                     unsigned short* __restrict__ rhi,
                                     unsigned short* __restrict__ rlo) {
    int idx = blockIdx.x * blockDim.x + threadIdx.x;
    if (idx >= N_NODES * HIDDEN) return;
    int i = idx >> 8, c = idx & 255;
    float h = ax[2 * i] * W1[c] + ax[2 * i + 1] * W1[HIDDEN + c] + b1[c];
    float r = fmaxf(h, 0.f);
    unsigned short hh, ll;
    bf_split(r, hh, ll);
    rhi[idx] = hh;
    rlo[idx] = ll;
}

// ---------------- W split+transpose (once per call): WT[n][k] bf16 hi/lo ----------------
__global__ void wsplit_kernel(const float* __restrict__ W2, const float* __restrict__ W3,
                              const float* __restrict__ W4,
                              unsigned short* __restrict__ whiT,
                              unsigned short* __restrict__ wloT) {
    int which = blockIdx.y;
    const float* W = (which == 0) ? W2 : ((which == 1) ? W3 : W4);
    unsigned short* hT = whiT + which * 65536;
    unsigned short* lT = wloT + which * 65536;
    int n = blockIdx.x, k = threadIdx.x;
    float v = W[k * 256 + n];
    unsigned short hh, ll;
    bf_split(v, hh, ll);
    hT[n * 256 + k] = hh;
    lT[n * 256 + k] = ll;
}

// ---------------- MFMA GEMM: t = r @ W via 3 split products, full-N tile ----------------
// t = rhi*Whi + rhi*Wlo + rlo*Whi. 128x256 tile (full N), 8 waves of 64x64, K-chunk 32.
// A-tile read once per 128-row strip (was twice with 128x128 grid): A traffic halved.
// XOR-swizzled LDS staging (R3-verified); fp16 output staged via LDS (union overlay).
__global__ __launch_bounds__(512) void mfma_gemm_kernel(const unsigned short* __restrict__ rhi,
                                                        const unsigned short* __restrict__ rlo,
                                                        const unsigned short* __restrict__ whiT,
                                                        const unsigned short* __restrict__ wloT,
                                                        __half* __restrict__ t) {
    union SMem {
        struct { short As[128][32]; short Bs[256][32]; } s; // 8 KB + 16 KB
        __half c[128][260];                                 // 66.6 KB output staging
    };
    __shared__ SMem sm;
    int tid = threadIdx.x;
    int row0 = blockIdx.x * 128;
    int lane = tid & 63;
    int wave = tid >> 6;          // 0..7
    int wm = wave & 1;            // row 64-tile
    int wn = wave >> 1;           // col 64-tile (0..3)
    int wq = lane >> 4, lm = lane & 15;

    const unsigned short* Aseg[3] = {rhi, rhi, rlo};
    const unsigned short* Bseg[3] = {whiT, wloT, whiT};

    // A staging: thread -> row tid>>2 (0..127), quad tid&3 (16B)
    int arow = tid >> 2;
    int aq = tid & 3;
    int ga = row0 + arow; if (ga >= N_NODES) ga = N_NODES - 1; // clamp; rows never stored
    size_t abase = (size_t)ga * 256 + aq * 8;
    int aswz = (aq ^ (arow & 3)) * 8;

    // B staging: thread -> col tid>>1 (0..255), quads {2h, 2h+1}
    int bcol = tid >> 1;
    int bh = (tid & 1) * 2;
    size_t bbase = (size_t)bcol * 256 + bh * 8;
    int bswz0 = ((bh + 0) ^ (bcol & 3)) * 8;
    int bswz1 = ((bh + 1) ^ (bcol & 3)) * 8;

    f32x4 acc[4][4];
#pragma unroll
    for (int mi = 0; mi < 4; ++mi)
#pragma unroll
        for (int ni = 0; ni < 4; ++ni) acc[mi][ni] = (f32x4)0.f;

    // prefetch chunk 0 (seg 0, kk 0)
    float4 a0 = *(const float4*)(rhi + abase);
    float4 b0 = *(const float4*)(whiT + bbase);
    float4 b1 = *(const float4*)(whiT + bbase + 8);

    int pfr = ((wq ^ (lm & 3)) * 8); // swizzled fragment read column

    for (int cc = 0; cc < 24; ++cc) {
        __syncthreads();
        *(float4*)&sm.s.As[arow][aswz] = a0;
        *(float4*)&sm.s.Bs[bcol][bswz0] = b0;
        *(float4*)&sm.s.Bs[bcol][bswz1] = b1;
        __syncthreads();
        if (cc + 1 < 24) {
            int nc = cc + 1;
            int sg = nc >> 3;
            int kk = (nc & 7) * 32;
            a0 = *(const float4*)(Aseg[sg] + abase + kk);
            b0 = *(const float4*)(Bseg[sg] + bbase + kk);
            b1 = *(const float4*)(Bseg[sg] + bbase + kk + 8);
        }
        bf16x8 af[4], bf[4];
#pragma unroll
        for (int mi = 0; mi < 4; ++mi)
            af[mi] = *(const bf16x8*)&sm.s.As[wm * 64 + mi * 16 + lm][pfr];
#pragma unroll
        for (int ni = 0; ni < 4; ++ni)
            bf[ni] = *(const bf16x8*)&sm.s.Bs[wn * 64 + ni * 16 + lm][pfr];
#pragma unroll
        for (int mi = 0; mi < 4; ++mi)
#pragma unroll
            for (int ni = 0; ni < 4; ++ni)
                acc[mi][ni] = __builtin_amdgcn_mfma_f32_16x16x32_bf16(af[mi], bf[ni],
                                                                      acc[mi][ni], 0, 0, 0);
    }

    // epilogue: acc -> fp16 tile in LDS (union overlay) -> coalesced 512B-row stores
    __syncthreads();
#pragma unroll
    for (int mi = 0; mi < 4; ++mi) {
        int rb = wm * 64 + mi * 16 + wq * 4;
#pragma unroll
        for (int ni = 0; ni < 4; ++ni) {
            int cb = wn * 64 + ni * 16 + lm;
#pragma unroll
            for (int r = 0; r < 4; ++r)
                sm.c[rb + r][cb] = __float2half(acc[mi][ni][r]);
        }
    }
    __syncthreads();
#pragma unroll
    for (int pass = 0; pass < 8; ++pass) {
        int row = pass * 16 + (tid >> 5);
        int gr = row0 + row;
        int ch = tid & 31;
        if (gr < N_NODES)
            *(uint4*)(t + (size_t)gr * 256 + ch * 8) = *(const uint4*)&sm.c[row][ch * 8];
    }
}

// ---------------- full-row aggregation, wave per node, fp16 gather ----------------
// out[i,:] = sum_e t[src,:]*w + t[i,:]*dinv^2 + b; epilogue: split-relu-bf16 or fp32 (LAST)
template <int LAST>
__global__ __launch_bounds__(256) void agg_full_kernel(const __half* __restrict__ t,
                                                       const int* __restrict__ rowptr,
                                                       const int* __restrict__ csr_src,
                                                       const float* __restrict__ csr_norm,
                                                       const float* __restrict__ dinv,
                                                       const float* __restrict__ bias,
                                                       float* __restrict__ hout,
                                                       unsigned short* __restrict__ rhi,
                                                       unsigned short* __restrict__ rlo) {
    int node = blockIdx.x * 4 + (threadIdx.x >> 6);
    if (node >= N_NODES) return;
    int lane = threadIdx.x & 63;
    int c = lane * 4;
    float di = dinv[node];
    float w0 = di * di;
    float4 v = h8load(t + (size_t)node * HIDDEN + c);
    float4 acc = make_float4(v.x * w0, v.y * w0, v.z * w0, v.w * w0);
    int e0 = rowptr[node], e1 = rowptr[node + 1];
    int p = e0;
    for (; p + 4 <= e1; p += 4) {
        int s0 = csr_src[p + 0], s1 = csr_src[p + 1];
        int s2 = csr_src[p + 2], s3 = csr_src[p + 3];
        float n0 = csr_norm[p + 0], n1 = csr_norm[p + 1];
        float n2 = csr_norm[p + 2], n3 = csr_norm[p + 3];
        float4 u0 = h8load(t + (size_t)s0 * HIDDEN + c);
        float4 u1 = h8load(t + (size_t)s1 * HIDDEN + c);
        float4 u2 = h8load(t + (size_t)s2 * HIDDEN + c);
        float4 u3 = h8load(t + (size_t)s3 * HIDDEN + c);
        acc.x += u0.x * n0; acc.y += u0.y * n0; acc.z += u0.z * n0; acc.w += u0.w * n0;
        acc.x += u1.x * n1; acc.y += u1.y * n1; acc.z += u1.z * n1; acc.w += u1.w * n1;
        acc.x += u2.x * n2; acc.y += u2.y * n2; acc.z += u2.z * n2; acc.w += u2.w * n2;
        acc.x += u3.x * n3; acc.y += u3.y * n3; acc.z += u3.z * n3; acc.w += u3.w * n3;
    }
    for (; p < e1; ++p) {
        int s = csr_src[p];
        float w = csr_norm[p];
        float4 u = h8load(t + (size_t)s * HIDDEN + c);
        acc.x += u.x * w; acc.y += u.y * w; acc.z += u.z * w; acc.w += u.w * w;
    }
    float4 b4 = *(const float4*)&bias[c];
    acc.x += b4.x; acc.y += b4.y; acc.z += b4.z; acc.w += b4.w;

    if (LAST) {
        *(float4*)&hout[(size_t)node * HIDDEN + c] = acc;
    } else {
        float r0 = fmaxf(acc.x, 0.f), r1 = fmaxf(acc.y, 0.f);
        float r2 = fmaxf(acc.z, 0.f), r3 = fmaxf(acc.w, 0.f);
        ushort4 h4, l4;
        bf_split(r0, h4.x, l4.x);
        bf_split(r1, h4.y, l4.y);
        bf_split(r2, h4.z, l4.z);
        bf_split(r3, h4.w, l4.w);
        *(ushort4*)&rhi[(size_t)node * HIDDEN + c] = h4;
        *(ushort4*)&rlo[(size_t)node * HIDDEN + c] = l4;
    }
}

// ---------------- pooling ----------------
__global__ void bounds_kernel(const int* __restrict__ batch, int* __restrict__ gbounds) {
    int i = blockIdx.x * blockDim.x + threadIdx.x;
    if (i >= N_NODES) return;
    int bi = batch[i];
    int bprev = (i == 0) ? -1 : batch[i - 1];
    for (int g = bprev + 1; g <= bi; ++g) gbounds[g] = i;
    if (i == N_NODES - 1) {
        for (int g = bi + 1; g <= N_GRAPHS; ++g) gbounds[g] = N_NODES;
    }
}

__global__ __launch_bounds__(256) void pool_kernel(const float* __restrict__ h,
                                                   const int* __restrict__ gbounds,
                                                   float* __restrict__ gsum) {
    int g = blockIdx.x;
    int c = threadIdx.x;
    int s = gbounds[g], e = gbounds[g + 1];
    float acc = 0.f;
    int i = s;
    for (; i + 4 <= e; i += 4) {
        float v0 = h[(size_t)(i + 0) * HIDDEN + c];
        float v1 = h[(size_t)(i + 1) * HIDDEN + c];
        float v2 = h[(size_t)(i + 2) * HIDDEN + c];
        float v3 = h[(size_t)(i + 3) * HIDDEN + c];
        acc += v0 + v1 + v2 + v3;
    }
    for (; i < e; ++i) acc += h[(size_t)i * HIDDEN + c];
    float cnt = (float)(e - s);
    gsum[g * HIDDEN + c] = acc / fmaxf(cnt, 1.f);
}

// ---------------- MLP head ----------------
__global__ __launch_bounds__(128) void mlp_kernel(const float* __restrict__ gsum,
                                                  const float* __restrict__ lin1_w,
                                                  const float* __restrict__ lin1_b,
                                                  const float* __restrict__ lin2_w,
                                                  const float* __restrict__ lin2_b,
                                                  float* __restrict__ out) {
    __shared__ float grow[HIDDEN];
    __shared__ float red[2];
    int g = blockIdx.x, j = threadIdx.x;
    grow[j] = gsum[g * HIDDEN + j];
    grow[j + 128] = gsum[g * HIDDEN + j + 128];
    __syncthreads();
    float acc = lin1_b[j];
    for (int k = 0; k < HIDDEN; ++k) acc += grow[k] * lin1_w[k * 128 + j];
    acc = fmaxf(acc, 0.f);
    float v = acc * lin2_w[j];
#pragma unroll
    for (int ofs = 32; ofs > 0; ofs >>= 1) v += __shfl_down(v, ofs, 64);
    if ((j & 63) == 0) red[j >> 6] = v;
    __syncthreads();
    if (j == 0) out[g] = red[0] + red[1] + lin2_b[0];
}

// ---------------- launch ----------------
extern "C" void kernel_launch(void* const* d_in, const int* in_sizes, int n_in,
                              void* d_out, int out_size, void* d_ws, size_t ws_size,
                              hipStream_t stream) {
    const float* x      = (const float*)d_in[0];
    const int*   ei     = (const int*)d_in[1];
    const int*   batch  = (const int*)d_in[2];
    const float* W1     = (const float*)d_in[3];
    const float* b1     = (const float*)d_in[4];
    const float* W2     = (const float*)d_in[5];
    const float* b2     = (const float*)d_in[6];
    const float* W3     = (const float*)d_in[7];
    const float* b3     = (const float*)d_in[8];
    const float* W4     = (const float*)d_in[9];
    const float* b4     = (const float*)d_in[10];
    const float* lin1_w = (const float*)d_in[11];
    const float* lin1_b = (const float*)d_in[12];
    const float* lin2_w = (const float*)d_in[13];
    const float* lin2_b = (const float*)d_in[14];
    float* out = (float*)d_out;

    char* ws = (char*)d_ws;
    size_t off = 0;
    auto alloc = [&](size_t bytes) -> void* {
        void* p = ws + off;
        off += (bytes + 255) & ~(size_t)255;
        return p;
    };
    __half*         tbuf   = (__half*)alloc((size_t)N_NODES * HIDDEN * 2);  // 25.6 MB fp16
    void*           rgn    = alloc((size_t)N_NODES * HIDDEN * 4);           // 51.2 MB (rhi+rlo | hfin)
    unsigned short* rhi    = (unsigned short*)rgn;
    unsigned short* rlo    = rhi + (size_t)N_NODES * HIDDEN;
    float*          hfin   = (float*)rgn;
    float* csr_norm = (float*)alloc((size_t)N_EDGES * 4);
    int*   csr_src  = (int*)alloc((size_t)N_EDGES * 4);
    int*   rowptr   = (int*)alloc((size_t)(N_NODES + 1) * 4);
    int*   deg      = (int*)alloc((size_t)N_NODES * 4);
    int*   cursor   = (int*)alloc((size_t)N_NODES * 4);
    float* dinv     = (float*)alloc((size_t)N_NODES * 4);
    float* ax       = (float*)alloc((size_t)N_NODES * 2 * 4);
    float* gsum     = (float*)alloc((size_t)N_GRAPHS * HIDDEN * 4);
    int*   gbounds  = (int*)alloc((size_t)(N_GRAPHS + 1) * 4);
    int*   bsums    = (int*)alloc((size_t)256 * 4);
    unsigned short* whiT = (unsigned short*)alloc((size_t)3 * 65536 * 2);
    unsigned short* wloT = (unsigned short*)alloc((size_t)3 * 65536 * 2);

    hipMemsetAsync(deg, 0, (size_t)N_NODES * 4, stream);
    hipMemsetAsync(cursor, 0, (size_t)N_NODES * 4, stream);

    const int TB = 256;
    const int NBLK = (N_NODES + 255) / 256;
    deg_count_kernel<<<(N_EDGES + TB - 1) / TB, TB, 0, stream>>>(ei, deg);
    block_scan_kernel<<<NBLK, 256, 0, stream>>>(deg, rowptr, bsums, dinv);
    scan_bsums_kernel<<<1, 256, 0, stream>>>(bsums, NBLK);
    add_offsets_kernel<<<NBLK, 256, 0, stream>>>(rowptr, bsums);
    fill_csr_kernel<<<(N_EDGES + TB - 1) / TB, TB, 0, stream>>>(ei, rowptr, cursor, dinv,
                                                                csr_src, csr_norm);
    wsplit_kernel<<<dim3(256, 3), 256, 0, stream>>>(W2, W3, W4, whiT, wloT);

    // conv1: (A x) W1 + b1 -> relu -> split bf16
    aggx_kernel<<<(N_NODES + TB - 1) / TB, TB, 0, stream>>>(x, rowptr, csr_src, csr_norm, dinv, ax);
    expand1_split_kernel<<<(N_NODES * HIDDEN) / TB, TB, 0, stream>>>(ax, W1, b1, rhi, rlo);

    // conv2..4: GEMM (split-bf16 MFMA, full-N tile, fp16 out) + full-row fp16-gather agg
    const int NGB = (N_NODES + 127) / 128;
    const int NAGG = (N_NODES + 3) / 4;
    const float* bs[3] = {b2, b3, b4};
    for (int l = 0; l < 3; ++l) {
        mfma_gemm_kernel<<<NGB, 512, 0, stream>>>(rhi, rlo, whiT + l * 65536,
                                                  wloT + l * 65536, tbuf);
        if (l < 2) {
            agg_full_kernel<0><<<NAGG, 256, 0, stream>>>(tbuf, rowptr, csr_src, csr_norm,
                                                         dinv, bs[l], nullptr, rhi, rlo);
        } else {
            agg_full_kernel<1><<<NAGG, 256, 0, stream>>>(tbuf, rowptr, csr_src, csr_norm,
                                                         dinv, bs[l], hfin, nullptr, nullptr);
        }
    }

    // pooling + head
    bounds_kernel<<<(N_NODES + TB - 1) / TB, TB, 0, stream>>>(batch, gbounds);
    pool_kernel<<<N_GRAPHS, 256, 0, stream>>>(hfin, gbounds, gsum);
    mlp_kernel<<<N_GRAPHS, 128, 0, stream>>>(gsum, lin1_w, lin1_b, lin2_w, lin2_b, out);
}